// Round 23
// baseline (100.332 us; speedup 1.0000x reference)
//
#include <hip/hip_runtime.h>

constexpr int DMODEL = 1024;
constexpr int NHEAD  = 16;
constexpr int DKH    = 64;
constexpr int BATCH  = 2;
constexpr int SEQ    = 2048;
constexpr int MTOT   = BATCH * SEQ;   // 4096
constexpr float SCL  = 0.18033688011112042f;   // (1/sqrt(64)) * log2(e)

typedef __attribute__((ext_vector_type(8)))  short short8;
typedef __attribute__((ext_vector_type(4)))  float floatx4;
typedef __attribute__((ext_vector_type(16))) float floatx16;
typedef __attribute__((ext_vector_type(4)))  uint  uintx4;

// fp32 -> bf16 round-to-nearest-even
__device__ __forceinline__ ushort f2bf(float f) {
    unsigned u = __builtin_bit_cast(unsigned, f);
    u = (u + 0x7fffu + ((u >> 16) & 1u)) >> 16;
    return (ushort)u;
}

// native 2^x (single v_exp_f32)
__device__ __forceinline__ float exp2n(float x) {
#if __has_builtin(__builtin_amdgcn_exp2f)
    return __builtin_amdgcn_exp2f(x);
#else
    float r;
    asm("v_exp_f32 %0, %1" : "=v"(r) : "v"(x));
    return r;
#endif
}

// async 16B global->LDS (HW writes lds_base + lane*16)
__device__ __forceinline__ void gld16(const ushort* g, ushort* l) {
    __builtin_amdgcn_global_load_lds(
        (const __attribute__((address_space(1))) void*)g,
        (__attribute__((address_space(3))) void*)l, 16, 0, 0);
}

// ---------------------------------------------------------------------------
// Convert pass: x -> xb bf16; Wq/Wk/Wv -> wc bf16 [3072,1024]; Wo -> wob bf16.
// Grid-stride: 2048 blocks x 4 iterations over 2M float4 (G11).
// ---------------------------------------------------------------------------
__global__ __launch_bounds__(256) void cvt_kernel(
    const float* __restrict__ x,  const float* __restrict__ wq,
    const float* __restrict__ wk, const float* __restrict__ wv,
    const float* __restrict__ wo,
    ushort* __restrict__ xb, ushort* __restrict__ wc, ushort* __restrict__ wob) {
#pragma unroll 1
    for (int id = blockIdx.x * 256 + threadIdx.x; id < (1 << 21);
         id += 2048 * 256) {
        const float* src;
        ushort* dst;
        if (id < (1 << 20)) {
            src = x + (size_t)id * 4;
            dst = xb + (size_t)id * 4;
        } else {
            const int t = id - (1 << 20);
            const int seg = t >> 18;                       // 0..3
            const size_t off = (size_t)(t & 0x3ffff) * 4;
            src = (seg == 0 ? wq : seg == 1 ? wk : seg == 2 ? wv : wo) + off;
            dst = (seg < 3) ? (wc + ((size_t)seg << 20) + off) : (wob + off);
        }
        const float4 v = *(const float4*)src;
        uint2 o;
        o.x = (uint)f2bf(v.x) | ((uint)f2bf(v.y) << 16);
        o.y = (uint)f2bf(v.z) | ((uint)f2bf(v.w) << 16);
        *(uint2*)dst = o;
    }
}

// ---------------------------------------------------------------------------
// bf16 GEMM  Y = A @ W^T + bias (NT).  BK=64, global_load_lds(16B), XOR
// swizzle via pre-swizzled global source, T3 double-buffered pipeline
// (prefetch next k-step before computing current; one __syncthreads per step).
// MODE 0: fused QKV epilogue; MODE 1: fp32 output.
// ---------------------------------------------------------------------------
template <int BMT, int MODE>
__global__ __launch_bounds__(256) void gemm_bf16(
    const ushort* __restrict__ A, const ushort* __restrict__ W,
    const float* __restrict__ bias0, const float* __restrict__ bias1,
    const float* __restrict__ bias2,
    ushort* __restrict__ Oq, ushort* __restrict__ Ok, ushort* __restrict__ Ov,
    float* __restrict__ Of) {
    constexpr int BM = 64 * BMT, BN = 128, BK = 64;
    constexpr int MI = 2 * BMT;
    constexpr int CA = BM / 8, CT = CA + BN / 8, NISS = CT / 4;
    constexpr int NKS = DMODEL / BK;                      // 16 k-steps
    __shared__ ushort Als[2][BM * BK];
    __shared__ ushort Bls[2][BN * BK];

    const int tid = threadIdx.x;
    const int w = tid >> 6, l = tid & 63;
    const int lr = l & 15, lg = l >> 4;
    const int wm = w >> 1, wn = w & 1;
    const int m0 = blockIdx.x * BM, n0 = blockIdx.y * BN;

    floatx4 acc[MI][4] = {};

    auto stage = [&](int ks, int buf) {
#pragma unroll
        for (int i = 0; i < NISS; i++) {
            const int c = w * NISS + i;
            const int cc = (c < CA) ? c : c - CA;
            const int row = (cc << 3) + (l >> 3);
            const int gcol = (((l & 7) ^ (row & 7)) << 3);
            if (c < CA)
                gld16(A + (size_t)(m0 + row) * DMODEL + ks * BK + gcol, &Als[buf][cc << 9]);
            else
                gld16(W + (size_t)(n0 + row) * DMODEL + ks * BK + gcol, &Bls[buf][cc << 9]);
        }
    };

    auto compute = [&](int buf) {
#pragma unroll
        for (int kk = 0; kk < 2; kk++) {
            short8 af[MI], bfv[4];
            const int u = kk * 4 + lg;
#pragma unroll
            for (int i = 0; i < MI; i++) {
                const int r = wm * (BM / 2) + i * 16 + lr;
                af[i] = *(const short8*)&Als[buf][r * 64 + ((u ^ (r & 7)) << 3)];
            }
#pragma unroll
            for (int j = 0; j < 4; j++) {
                const int r = wn * 64 + j * 16 + lr;
                bfv[j] = *(const short8*)&Bls[buf][r * 64 + ((u ^ (r & 7)) << 3)];
            }
            __builtin_amdgcn_s_setprio(1);
#pragma unroll
            for (int i = 0; i < MI; i++)
#pragma unroll
                for (int j = 0; j < 4; j++)
                    acc[i][j] = __builtin_amdgcn_mfma_f32_16x16x32_bf16(af[i], bfv[j], acc[i][j], 0, 0, 0);
            __builtin_amdgcn_s_setprio(0);
        }
    };

    stage(0, 0);
    __syncthreads();
#pragma unroll 1
    for (int ks = 0; ks < NKS - 1; ks++) {
        stage(ks + 1, (ks + 1) & 1);
        compute(ks & 1);
        __syncthreads();
    }
    compute((NKS - 1) & 1);

#pragma unroll
    for (int i = 0; i < MI; i++) {
        const int rbase = m0 + wm * (BM / 2) + i * 16 + lg * 4;
#pragma unroll
        for (int j = 0; j < 4; j++) {
            const int cg = n0 + wn * 64 + j * 16 + lr;
            if constexpr (MODE == 1) {
                const float bb = bias0[cg];
#pragma unroll
                for (int p = 0; p < 4; p++)
                    Of[(size_t)(rbase + p) * DMODEL + cg] = acc[i][j][p] + bb;
            } else {
                const int sel = cg >> 10, cw = cg & 1023;
                const int h = cw >> 6, d = cw & 63;
                const float bb = (sel == 0 ? bias0 : sel == 1 ? bias1 : bias2)[cw];
                const int b = rbase >> 11, s = rbase & (SEQ - 1);
                if (sel == 2) {
                    uint2 pk;
                    pk.x = (uint)f2bf(acc[i][j][0] + bb) | ((uint)f2bf(acc[i][j][1] + bb) << 16);
                    pk.y = (uint)f2bf(acc[i][j][2] + bb) | ((uint)f2bf(acc[i][j][3] + bb) << 16);
                    *(uint2*)&Ov[((size_t)(b * NHEAD + h) * DKH + d) * SEQ + s] = pk;
                } else if (sel == 0) {
                    uint2 pk;
                    pk.x = (uint)f2bf((acc[i][j][0] + bb) * SCL) |
                           ((uint)f2bf((acc[i][j][1] + bb) * SCL) << 16);
                    pk.y = (uint)f2bf((acc[i][j][2] + bb) * SCL) |
                           ((uint)f2bf((acc[i][j][3] + bb) * SCL) << 16);
                    *(uint2*)&Oq[((size_t)(b * NHEAD + h) * DKH + d) * SEQ + s] = pk;
                } else {
#pragma unroll
                    for (int p = 0; p < 4; p++)
                        Ok[((size_t)(b * NHEAD + h) * SEQ + s + p) * DKH + d] = f2bf(acc[i][j][p] + bb);
                }
            }
        }
    }
}

// ---------------------------------------------------------------------------
// Flash attention (r19 99.5us config): 32x32x16 + NO-MAX softmax (native
// v_exp_f32) + in-block k-split with pure-sum merge + 32-k halves + T3 dbuf
// + ones-MFMA l-sum (r22 A/B: better than VALU l-sum).
// NEW: symmetric merge epilogue — each k-group writes its own d-half
// (wg0: d0..31 via wg1's acc0; wg1: d32..63 via wg0's acc1).
// 8 waves = 2 k-groups x 4 q-waves; 512 blocks; 16 waves/CU.
// Q input TRANSPOSED [B,H,64,S] (pre-scaled by SCL).
// ---------------------------------------------------------------------------
__global__ __launch_bounds__(512, 4) void attn_kernel(
    const ushort* __restrict__ Qt, const ushort* __restrict__ K,
    const ushort* __restrict__ Vt, ushort* __restrict__ O) {
    constexpr int KT = 64, NT = SEQ / KT, NTG = NT / 2;   // 16 tiles/group
    __shared__ ushort Kls[2][2][KT * 64];   // [group][dbuf], swizzled slots
    __shared__ ushort Vls[2][2][KT * 64];

    const int tid = threadIdx.x;
    const int w = tid >> 6, l = tid & 63;
    const int wl = w & 3, wg = w >> 2;
    const int q32 = l & 31, hl = l >> 5, l7 = l & 7;
    // T1 remap: same-head blocks share an XCD (512 blocks)
    const int l0 = blockIdx.x;
    const int bh = (l0 & 7) + ((l0 >> 7) << 3);
    const int q0 = ((l0 >> 3) & 15) * 128;
    const int qb = q0 + wl * 32;                      // wave's 32-q base
    const ushort* Qh = Qt + (size_t)bh * DKH * SEQ;
    const ushort* Kh = K  + (size_t)bh * SEQ * DKH;
    const ushort* Vh = Vt + (size_t)bh * DKH * SEQ;

    // Q B-frags (QK^T): qf[c] elem j = Q^T[d = 16c + 8*hl + j][q = qb + q32]
    short8 qf[4];
#pragma unroll
    for (int c = 0; c < 4; c++)
#pragma unroll
        for (int j = 0; j < 8; j++)
            ((ushort*)&qf[c])[j] = Qh[(size_t)(16 * c + 8 * hl + j) * SEQ + qb + q32];

    // bf16 ones vector for the l-sum MFMA
    short8 ones;
#pragma unroll
    for (int j = 0; j < 8; j++) ones[j] = (short)0x3F80;

    // staging: wave wl stages rows wl*16..wl*16+15 of its group's tile
    const int sr8 = l >> 3;
    const int scol = ((l & 7) ^ (sr8 & 7)) * 8;       // pre-swizzled source col
    const ushort* Kg = Kh + (size_t)(wl * 16 + sr8) * DKH + scol;
    const ushort* Vg = Vh + (size_t)(wl * 16 + sr8) * SEQ + scol;

    floatx16 acc0 = {}, acc1 = {}, accl = {};

    auto stage = [&](int t, int buf) {                // t = absolute tile index
        ushort* kd = &Kls[wg][buf][0];
        ushort* vd = &Vls[wg][buf][0];
        gld16(Kg + (size_t)t * (KT * DKH),           kd + wl * 1024);
        gld16(Kg + (size_t)t * (KT * DKH) + 8 * DKH, kd + wl * 1024 + 512);
        gld16(Vg + (size_t)t * KT,                   vd + wl * 1024);
        gld16(Vg + (size_t)t * KT + 8 * SEQ,         vd + wl * 1024 + 512);
    };

    auto compute = [&](int buf) {
        const ushort* kb = &Kls[wg][buf][0];
        const ushort* vb = &Vls[wg][buf][0];
#pragma unroll
        for (int h = 0; h < 2; h++) {                 // 32-k half
            // ---- QK^T half: sa = S^T[k = 32h..32h+31][q]
            floatx16 sa = {};
            __builtin_amdgcn_s_setprio(1);
#pragma unroll
            for (int c = 0; c < 4; c++) {
                const int sl = (((2 * c + hl) ^ l7) << 3);
                const short8 kf = *(const short8*)&kb[(h * 32 + q32) * 64 + sl];
                sa = __builtin_amdgcn_mfma_f32_32x32x16_bf16(kf, qf[c], sa, 0, 0, 0);
            }
            __builtin_amdgcn_s_setprio(0);

            // ---- NO-MAX softmax: P = exp2(s) via native v_exp_f32
#pragma unroll
            for (int i = 0; i < 16; i++) sa[i] = exp2n(sa[i]);

            // ---- P -> bf16 in-register + permlane32_swap lane-exchange
            uint wd[8];
#pragma unroll
            for (int m = 0; m < 8; m++)
                asm("v_cvt_pk_bf16_f32 %0, %1, %2"
                    : "=v"(wd[m]) : "v"(sa[2 * m]), "v"(sa[2 * m + 1]));
            asm volatile("v_permlane32_swap_b32 %0, %1" : "+v"(wd[0]), "+v"(wd[2]));
            asm volatile("v_permlane32_swap_b32 %0, %1" : "+v"(wd[1]), "+v"(wd[3]));
            asm volatile("v_permlane32_swap_b32 %0, %1" : "+v"(wd[4]), "+v"(wd[6]));
            asm volatile("v_permlane32_swap_b32 %0, %1" : "+v"(wd[5]), "+v"(wd[7]));
            uintx4 f0 = {wd[0], wd[1], wd[2], wd[3]};
            uintx4 f1 = {wd[4], wd[5], wd[6], wd[7]};
            const short8 pf0 = __builtin_bit_cast(short8, f0);
            const short8 pf1 = __builtin_bit_cast(short8, f1);

            // ---- PV + l-sum for this half's two k-slices
            __builtin_amdgcn_s_setprio(1);
#pragma unroll
            for (int c2 = 0; c2 < 2; c2++) {
                const int c = h * 2 + c2;
                const int sl = (((2 * c + hl) ^ l7) << 3);
                const short8 pfc = c2 ? pf1 : pf0;
                const short8 vf0 = *(const short8*)&vb[q32 * 64 + sl];
                const short8 vf1 = *(const short8*)&vb[(32 + q32) * 64 + sl];
                acc0 = __builtin_amdgcn_mfma_f32_32x32x16_bf16(vf0, pfc, acc0, 0, 0, 0);
                acc1 = __builtin_amdgcn_mfma_f32_32x32x16_bf16(vf1, pfc, acc1, 0, 0, 0);
                accl = __builtin_amdgcn_mfma_f32_32x32x16_bf16(ones, pfc, accl, 0, 0, 0);
            }
            __builtin_amdgcn_s_setprio(0);
        }
    };

    // T3-minimum pipeline over this group's 16 tiles (base = wg*16)
    const int tb = wg * NTG;
    stage(tb, 0);
    __syncthreads();
#pragma unroll 1
    for (int it = 0; it < NTG / 2 - 1; it++) {
        stage(tb + 2 * it + 1, 1);
        compute(0);
        __syncthreads();
        stage(tb + 2 * it + 2, 0);
        compute(1);
        __syncthreads();
    }
    stage(tb + NTG - 1, 1);
    compute(0);
    __syncthreads();
    compute(1);

    // ---- symmetric merge (pure sum): each group writes its own d-half.
    // wg1 exports {l, acc0} in smA; wg0 exports {l, acc1} in smB.
    __syncthreads();
    float* smA = (float*)&Kls[0][0][0];   // 256 * 17 floats = 17.4KB
    float* smB = (float*)&Vls[0][0][0];   // 256 * 17 floats
    const int li = wl * 64 + l;           // 0..255
    if (wg == 1) {
        float* pa = smA + (size_t)li * 17;
        pa[0] = accl[0];
#pragma unroll
        for (int i = 0; i < 16; i++) pa[1 + i] = acc0[i];
    } else {
        float* pb = smB + (size_t)li * 17;
        pb[0] = accl[0];
#pragma unroll
        for (int i = 0; i < 16; i++) pb[1 + i] = acc1[i];
    }
    __syncthreads();
    const int b = bh >> 4, h = bh & (NHEAD - 1);
    ushort* Ob = O + (size_t)(b * SEQ + qb + q32) * DMODEL + h * DKH;
    if (wg == 0) {
        const float* pa = smA + (size_t)li * 17;
        const float inv = 1.0f / (accl[0] + pa[0]);
#pragma unroll
        for (int u = 0; u < 4; u++) {
            const float v0 = (acc0[4 * u]     + pa[1 + 4 * u])     * inv;
            const float v1 = (acc0[4 * u + 1] + pa[1 + 4 * u + 1]) * inv;
            const float v2 = (acc0[4 * u + 2] + pa[1 + 4 * u + 2]) * inv;
            const float v3 = (acc0[4 * u + 3] + pa[1 + 4 * u + 3]) * inv;
            uint2 pk;
            pk.x = (uint)f2bf(v0) | ((uint)f2bf(v1) << 16);
            pk.y = (uint)f2bf(v2) | ((uint)f2bf(v3) << 16);
            *(uint2*)&Ob[u * 8 + hl * 4] = pk;
        }
    } else {
        const float* pb = smB + (size_t)li * 17;
        const float inv = 1.0f / (accl[0] + pb[0]);
#pragma unroll
        for (int u = 0; u < 4; u++) {
            const float v0 = (acc1[4 * u]     + pb[1 + 4 * u])     * inv;
            const float v1 = (acc1[4 * u + 1] + pb[1 + 4 * u + 1]) * inv;
            const float v2 = (acc1[4 * u + 2] + pb[1 + 4 * u + 2]) * inv;
            const float v3 = (acc1[4 * u + 3] + pb[1 + 4 * u + 3]) * inv;
            uint2 pk;
            pk.x = (uint)f2bf(v0) | ((uint)f2bf(v1) << 16);
            pk.y = (uint)f2bf(v2) | ((uint)f2bf(v3) << 16);
            *(uint2*)&Ob[32 + u * 8 + hl * 4] = pk;
        }
    }
}

// ---------------------------------------------------------------------------
extern "C" void kernel_launch(void* const* d_in, const int* in_sizes, int n_in,
                              void* d_out, int out_size, void* d_ws, size_t ws_size,
                              hipStream_t stream) {
    const float* x  = (const float*)d_in[0];
    const float* Wq = (const float*)d_in[1];
    const float* bq = (const float*)d_in[2];
    const float* Wk = (const float*)d_in[3];
    const float* bk = (const float*)d_in[4];
    const float* Wv = (const float*)d_in[5];
    const float* bv = (const float*)d_in[6];
    const float* Wo = (const float*)d_in[7];
    const float* bo = (const float*)d_in[8];

    ushort* base = (ushort*)d_ws;
    ushort* xb  = base;                                  // 4M bf16
    ushort* wc  = xb  + (size_t)4 * 1024 * 1024;         // 3M  (Wq|Wk|Wv)
    ushort* wob = wc  + (size_t)3 * 1024 * 1024;         // 1M
    ushort* qws = wob + (size_t)1 * 1024 * 1024;         // 4M  Q^T [B,H,64,S] (pre-scaled)
    ushort* kws = qws + (size_t)4 * 1024 * 1024;         // 4M  K [B,H,S,64]
    ushort* vws = kws + (size_t)4 * 1024 * 1024;         // 4M  V^T [B,H,64,S]
    ushort* aws = vws + (size_t)4 * 1024 * 1024;         // 4M  attn out bf16

    hipLaunchKernelGGL(cvt_kernel, dim3(2048), dim3(256), 0, stream,
                       x, Wq, Wk, Wv, Wo, xb, wc, wob);

    hipLaunchKernelGGL((gemm_bf16<2, 0>), dim3(MTOT / 128, 3072 / 128), dim3(256), 0, stream,
                       xb, wc, bq, bk, bv, qws, kws, vws, (float*)nullptr);

    hipLaunchKernelGGL(attn_kernel, dim3(512), dim3(512), 0, stream,
                       qws, kws, vws, aws);

    hipLaunchKernelGGL((gemm_bf16<1, 1>), dim3(MTOT / 64, DMODEL / 128), dim3(256), 0, stream,
                       aws, wob, bo, (const float*)nullptr, (const float*)nullptr,
                       (ushort*)nullptr, (ushort*)nullptr, (ushort*)nullptr, (float*)d_out);
}

// Round 24
// 99.371 us; speedup vs baseline: 1.0097x; 1.0097x over previous
//
#include <hip/hip_runtime.h>

constexpr int DMODEL = 1024;
constexpr int NHEAD  = 16;
constexpr int DKH    = 64;
constexpr int BATCH  = 2;
constexpr int SEQ    = 2048;
constexpr int MTOT   = BATCH * SEQ;   // 4096
constexpr float SCL  = 0.18033688011112042f;   // (1/sqrt(64)) * log2(e)

typedef __attribute__((ext_vector_type(8)))  short short8;
typedef __attribute__((ext_vector_type(4)))  float floatx4;
typedef __attribute__((ext_vector_type(16))) float floatx16;
typedef __attribute__((ext_vector_type(4)))  uint  uintx4;

// fp32 -> bf16 round-to-nearest-even
__device__ __forceinline__ ushort f2bf(float f) {
    unsigned u = __builtin_bit_cast(unsigned, f);
    u = (u + 0x7fffu + ((u >> 16) & 1u)) >> 16;
    return (ushort)u;
}

// native 2^x (single v_exp_f32)
__device__ __forceinline__ float exp2n(float x) {
#if __has_builtin(__builtin_amdgcn_exp2f)
    return __builtin_amdgcn_exp2f(x);
#else
    float r;
    asm("v_exp_f32 %0, %1" : "=v"(r) : "v"(x));
    return r;
#endif
}

// async 16B global->LDS (HW writes lds_base + lane*16)
__device__ __forceinline__ void gld16(const ushort* g, ushort* l) {
    __builtin_amdgcn_global_load_lds(
        (const __attribute__((address_space(1))) void*)g,
        (__attribute__((address_space(3))) void*)l, 16, 0, 0);
}

// ---------------------------------------------------------------------------
// Convert pass: x -> xb bf16; Wq/Wk/Wv -> wc bf16 [3072,1024]; Wo -> wob bf16.
// ---------------------------------------------------------------------------
__global__ __launch_bounds__(256) void cvt_kernel(
    const float* __restrict__ x,  const float* __restrict__ wq,
    const float* __restrict__ wk, const float* __restrict__ wv,
    const float* __restrict__ wo,
    ushort* __restrict__ xb, ushort* __restrict__ wc, ushort* __restrict__ wob) {
    const int id = blockIdx.x * 256 + threadIdx.x;        // 0 .. 2M-1
    const float* src;
    ushort* dst;
    if (id < (1 << 20)) {
        src = x + (size_t)id * 4;
        dst = xb + (size_t)id * 4;
    } else {
        const int t = id - (1 << 20);
        const int seg = t >> 18;                           // 0..3
        const size_t off = (size_t)(t & 0x3ffff) * 4;
        src = (seg == 0 ? wq : seg == 1 ? wk : seg == 2 ? wv : wo) + off;
        dst = (seg < 3) ? (wc + ((size_t)seg << 20) + off) : (wob + off);
    }
    const float4 v = *(const float4*)src;
    uint2 o;
    o.x = (uint)f2bf(v.x) | ((uint)f2bf(v.y) << 16);
    o.y = (uint)f2bf(v.z) | ((uint)f2bf(v.w) << 16);
    *(uint2*)dst = o;
}

// ---------------------------------------------------------------------------
// bf16 GEMM  Y = A @ W^T + bias (NT).  BK=64, global_load_lds(16B), XOR
// swizzle via pre-swizzled global source, T3 double-buffered pipeline
// (prefetch next k-step before computing current; one __syncthreads per step).
// MODE 0: fused QKV epilogue; MODE 1: fp32 output.
// ---------------------------------------------------------------------------
template <int BMT, int MODE>
__global__ __launch_bounds__(256) void gemm_bf16(
    const ushort* __restrict__ A, const ushort* __restrict__ W,
    const float* __restrict__ bias0, const float* __restrict__ bias1,
    const float* __restrict__ bias2,
    ushort* __restrict__ Oq, ushort* __restrict__ Ok, ushort* __restrict__ Ov,
    float* __restrict__ Of) {
    constexpr int BM = 64 * BMT, BN = 128, BK = 64;
    constexpr int MI = 2 * BMT;
    constexpr int CA = BM / 8, CT = CA + BN / 8, NISS = CT / 4;
    constexpr int NKS = DMODEL / BK;                      // 16 k-steps
    __shared__ ushort Als[2][BM * BK];
    __shared__ ushort Bls[2][BN * BK];

    const int tid = threadIdx.x;
    const int w = tid >> 6, l = tid & 63;
    const int lr = l & 15, lg = l >> 4;
    const int wm = w >> 1, wn = w & 1;
    const int m0 = blockIdx.x * BM, n0 = blockIdx.y * BN;

    floatx4 acc[MI][4] = {};

    auto stage = [&](int ks, int buf) {
#pragma unroll
        for (int i = 0; i < NISS; i++) {
            const int c = w * NISS + i;
            const int cc = (c < CA) ? c : c - CA;
            const int row = (cc << 3) + (l >> 3);
            const int gcol = (((l & 7) ^ (row & 7)) << 3);
            if (c < CA)
                gld16(A + (size_t)(m0 + row) * DMODEL + ks * BK + gcol, &Als[buf][cc << 9]);
            else
                gld16(W + (size_t)(n0 + row) * DMODEL + ks * BK + gcol, &Bls[buf][cc << 9]);
        }
    };

    auto compute = [&](int buf) {
#pragma unroll
        for (int kk = 0; kk < 2; kk++) {
            short8 af[MI], bfv[4];
            const int u = kk * 4 + lg;
#pragma unroll
            for (int i = 0; i < MI; i++) {
                const int r = wm * (BM / 2) + i * 16 + lr;
                af[i] = *(const short8*)&Als[buf][r * 64 + ((u ^ (r & 7)) << 3)];
            }
#pragma unroll
            for (int j = 0; j < 4; j++) {
                const int r = wn * 64 + j * 16 + lr;
                bfv[j] = *(const short8*)&Bls[buf][r * 64 + ((u ^ (r & 7)) << 3)];
            }
            __builtin_amdgcn_s_setprio(1);
#pragma unroll
            for (int i = 0; i < MI; i++)
#pragma unroll
                for (int j = 0; j < 4; j++)
                    acc[i][j] = __builtin_amdgcn_mfma_f32_16x16x32_bf16(af[i], bfv[j], acc[i][j], 0, 0, 0);
            __builtin_amdgcn_s_setprio(0);
        }
    };

    stage(0, 0);
    __syncthreads();
#pragma unroll 1
    for (int ks = 0; ks < NKS - 1; ks++) {
        stage(ks + 1, (ks + 1) & 1);
        compute(ks & 1);
        __syncthreads();
    }
    compute((NKS - 1) & 1);

#pragma unroll
    for (int i = 0; i < MI; i++) {
        const int rbase = m0 + wm * (BM / 2) + i * 16 + lg * 4;
#pragma unroll
        for (int j = 0; j < 4; j++) {
            const int cg = n0 + wn * 64 + j * 16 + lr;
            if constexpr (MODE == 1) {
                const float bb = bias0[cg];
#pragma unroll
                for (int p = 0; p < 4; p++)
                    Of[(size_t)(rbase + p) * DMODEL + cg] = acc[i][j][p] + bb;
            } else {
                const int sel = cg >> 10, cw = cg & 1023;
                const int h = cw >> 6, d = cw & 63;
                const float bb = (sel == 0 ? bias0 : sel == 1 ? bias1 : bias2)[cw];
                const int b = rbase >> 11, s = rbase & (SEQ - 1);
                if (sel == 2) {
                    uint2 pk;
                    pk.x = (uint)f2bf(acc[i][j][0] + bb) | ((uint)f2bf(acc[i][j][1] + bb) << 16);
                    pk.y = (uint)f2bf(acc[i][j][2] + bb) | ((uint)f2bf(acc[i][j][3] + bb) << 16);
                    *(uint2*)&Ov[((size_t)(b * NHEAD + h) * DKH + d) * SEQ + s] = pk;
                } else if (sel == 0) {
                    uint2 pk;
                    pk.x = (uint)f2bf((acc[i][j][0] + bb) * SCL) |
                           ((uint)f2bf((acc[i][j][1] + bb) * SCL) << 16);
                    pk.y = (uint)f2bf((acc[i][j][2] + bb) * SCL) |
                           ((uint)f2bf((acc[i][j][3] + bb) * SCL) << 16);
                    *(uint2*)&Oq[((size_t)(b * NHEAD + h) * DKH + d) * SEQ + s] = pk;
                } else {
#pragma unroll
                    for (int p = 0; p < 4; p++)
                        Ok[((size_t)(b * NHEAD + h) * SEQ + s + p) * DKH + d] = f2bf(acc[i][j][p] + bb);
                }
            }
        }
    }
}

// ---------------------------------------------------------------------------
// Flash attention (champion r19 config): 32x32x16 swapped QK^T + NO-MAX
// softmax (native v_exp_f32) + in-block k-split with pure-sum merge + 32-k
// halves (spill-free) + T3 dbuf + ones-MFMA l-sum + T5 setprio + T1 remap.
// 8 waves = 2 k-groups x 4 q-waves; 512 blocks; 16 waves/CU.
// Q input TRANSPOSED [B,H,64,S] (pre-scaled by SCL).
// ---------------------------------------------------------------------------
__global__ __launch_bounds__(512, 4) void attn_kernel(
    const ushort* __restrict__ Qt, const ushort* __restrict__ K,
    const ushort* __restrict__ Vt, ushort* __restrict__ O) {
    constexpr int KT = 64, NT = SEQ / KT, NTG = NT / 2;   // 16 tiles/group
    __shared__ ushort Kls[2][2][KT * 64];   // [group][dbuf], swizzled slots
    __shared__ ushort Vls[2][2][KT * 64];

    const int tid = threadIdx.x;
    const int w = tid >> 6, l = tid & 63;
    const int wl = w & 3, wg = w >> 2;
    const int q32 = l & 31, hl = l >> 5, l7 = l & 7;
    // T1 remap: same-head blocks share an XCD (512 blocks)
    const int l0 = blockIdx.x;
    const int bh = (l0 & 7) + ((l0 >> 7) << 3);
    const int q0 = ((l0 >> 3) & 15) * 128;
    const int qb = q0 + wl * 32;                      // wave's 32-q base
    const ushort* Qh = Qt + (size_t)bh * DKH * SEQ;
    const ushort* Kh = K  + (size_t)bh * SEQ * DKH;
    const ushort* Vh = Vt + (size_t)bh * DKH * SEQ;

    // Q B-frags (QK^T): qf[c] elem j = Q^T[d = 16c + 8*hl + j][q = qb + q32]
    short8 qf[4];
#pragma unroll
    for (int c = 0; c < 4; c++)
#pragma unroll
        for (int j = 0; j < 8; j++)
            ((ushort*)&qf[c])[j] = Qh[(size_t)(16 * c + 8 * hl + j) * SEQ + qb + q32];

    // bf16 ones vector for the l-sum MFMA
    short8 ones;
#pragma unroll
    for (int j = 0; j < 8; j++) ones[j] = (short)0x3F80;

    // staging: wave wl stages rows wl*16..wl*16+15 of its group's tile
    const int sr8 = l >> 3;
    const int scol = ((l & 7) ^ (sr8 & 7)) * 8;       // pre-swizzled source col
    const ushort* Kg = Kh + (size_t)(wl * 16 + sr8) * DKH + scol;
    const ushort* Vg = Vh + (size_t)(wl * 16 + sr8) * SEQ + scol;

    floatx16 acc0 = {}, acc1 = {}, accl = {};

    auto stage = [&](int t, int buf) {                // t = absolute tile index
        ushort* kd = &Kls[wg][buf][0];
        ushort* vd = &Vls[wg][buf][0];
        gld16(Kg + (size_t)t * (KT * DKH),           kd + wl * 1024);
        gld16(Kg + (size_t)t * (KT * DKH) + 8 * DKH, kd + wl * 1024 + 512);
        gld16(Vg + (size_t)t * KT,                   vd + wl * 1024);
        gld16(Vg + (size_t)t * KT + 8 * SEQ,         vd + wl * 1024 + 512);
    };

    auto compute = [&](int buf) {
        const ushort* kb = &Kls[wg][buf][0];
        const ushort* vb = &Vls[wg][buf][0];
#pragma unroll
        for (int h = 0; h < 2; h++) {                 // 32-k half
            // ---- QK^T half: sa = S^T[k = 32h..32h+31][q]
            floatx16 sa = {};
            __builtin_amdgcn_s_setprio(1);
#pragma unroll
            for (int c = 0; c < 4; c++) {
                const int sl = (((2 * c + hl) ^ l7) << 3);
                const short8 kf = *(const short8*)&kb[(h * 32 + q32) * 64 + sl];
                sa = __builtin_amdgcn_mfma_f32_32x32x16_bf16(kf, qf[c], sa, 0, 0, 0);
            }
            __builtin_amdgcn_s_setprio(0);

            // ---- NO-MAX softmax: P = exp2(s) via native v_exp_f32
#pragma unroll
            for (int i = 0; i < 16; i++) sa[i] = exp2n(sa[i]);

            // ---- P -> bf16 in-register + permlane32_swap lane-exchange
            uint wd[8];
#pragma unroll
            for (int m = 0; m < 8; m++)
                asm("v_cvt_pk_bf16_f32 %0, %1, %2"
                    : "=v"(wd[m]) : "v"(sa[2 * m]), "v"(sa[2 * m + 1]));
            asm volatile("v_permlane32_swap_b32 %0, %1" : "+v"(wd[0]), "+v"(wd[2]));
            asm volatile("v_permlane32_swap_b32 %0, %1" : "+v"(wd[1]), "+v"(wd[3]));
            asm volatile("v_permlane32_swap_b32 %0, %1" : "+v"(wd[4]), "+v"(wd[6]));
            asm volatile("v_permlane32_swap_b32 %0, %1" : "+v"(wd[5]), "+v"(wd[7]));
            uintx4 f0 = {wd[0], wd[1], wd[2], wd[3]};
            uintx4 f1 = {wd[4], wd[5], wd[6], wd[7]};
            const short8 pf0 = __builtin_bit_cast(short8, f0);
            const short8 pf1 = __builtin_bit_cast(short8, f1);

            // ---- PV + l-sum for this half's two k-slices
            __builtin_amdgcn_s_setprio(1);
#pragma unroll
            for (int c2 = 0; c2 < 2; c2++) {
                const int c = h * 2 + c2;
                const int sl = (((2 * c + hl) ^ l7) << 3);
                const short8 pfc = c2 ? pf1 : pf0;
                const short8 vf0 = *(const short8*)&vb[q32 * 64 + sl];
                const short8 vf1 = *(const short8*)&vb[(32 + q32) * 64 + sl];
                acc0 = __builtin_amdgcn_mfma_f32_32x32x16_bf16(vf0, pfc, acc0, 0, 0, 0);
                acc1 = __builtin_amdgcn_mfma_f32_32x32x16_bf16(vf1, pfc, acc1, 0, 0, 0);
                accl = __builtin_amdgcn_mfma_f32_32x32x16_bf16(ones, pfc, accl, 0, 0, 0);
            }
            __builtin_amdgcn_s_setprio(0);
        }
    };

    // T3-minimum pipeline over this group's 16 tiles (base = wg*16)
    const int tb = wg * NTG;
    stage(tb, 0);
    __syncthreads();
#pragma unroll 1
    for (int it = 0; it < NTG / 2 - 1; it++) {
        stage(tb + 2 * it + 1, 1);
        compute(0);
        __syncthreads();
        stage(tb + 2 * it + 2, 0);
        compute(1);
        __syncthreads();
    }
    stage(tb + NTG - 1, 1);
    compute(0);
    __syncthreads();
    compute(1);

    // ---- merge: pure sum of the two k-halves (no-max softmax => no rescale)
    __syncthreads();
    float* smA = (float*)&Kls[0][0][0];   // 17 floats/lane: l, acc0
    float* smB = (float*)&Vls[0][0][0];   // 16 floats/lane: acc1
    const int li = wl * 64 + l;           // 0..255
    if (wg == 1) {
        float* pa = smA + (size_t)li * 17;
        pa[0] = accl[0];
#pragma unroll
        for (int i = 0; i < 16; i++) pa[1 + i] = acc0[i];
        float* pb = smB + (size_t)li * 16;
#pragma unroll
        for (int i = 0; i < 16; i++) pb[i] = acc1[i];
    }
    __syncthreads();
    if (wg == 0) {
        const float* pa = smA + (size_t)li * 17;
        const float* pb = smB + (size_t)li * 16;
        const float inv = 1.0f / (accl[0] + pa[0]);
        const int b = bh >> 4, h = bh & (NHEAD - 1);
        ushort* Ob = O + (size_t)(b * SEQ + qb + q32) * DMODEL + h * DKH;
#pragma unroll
        for (int u = 0; u < 4; u++) {
            const float v0 = (acc0[4 * u]     + pa[1 + 4 * u])     * inv;
            const float v1 = (acc0[4 * u + 1] + pa[1 + 4 * u + 1]) * inv;
            const float v2 = (acc0[4 * u + 2] + pa[1 + 4 * u + 2]) * inv;
            const float v3 = (acc0[4 * u + 3] + pa[1 + 4 * u + 3]) * inv;
            uint2 pk;
            pk.x = (uint)f2bf(v0) | ((uint)f2bf(v1) << 16);
            pk.y = (uint)f2bf(v2) | ((uint)f2bf(v3) << 16);
            *(uint2*)&Ob[u * 8 + hl * 4] = pk;
        }
#pragma unroll
        for (int u = 0; u < 4; u++) {
            const float v0 = (acc1[4 * u]     + pb[4 * u])     * inv;
            const float v1 = (acc1[4 * u + 1] + pb[4 * u + 1]) * inv;
            const float v2 = (acc1[4 * u + 2] + pb[4 * u + 2]) * inv;
            const float v3 = (acc1[4 * u + 3] + pb[4 * u + 3]) * inv;
            uint2 pk;
            pk.x = (uint)f2bf(v0) | ((uint)f2bf(v1) << 16);
            pk.y = (uint)f2bf(v2) | ((uint)f2bf(v3) << 16);
            *(uint2*)&Ob[32 + u * 8 + hl * 4] = pk;
        }
    }
}

// ---------------------------------------------------------------------------
extern "C" void kernel_launch(void* const* d_in, const int* in_sizes, int n_in,
                              void* d_out, int out_size, void* d_ws, size_t ws_size,
                              hipStream_t stream) {
    const float* x  = (const float*)d_in[0];
    const float* Wq = (const float*)d_in[1];
    const float* bq = (const float*)d_in[2];
    const float* Wk = (const float*)d_in[3];
    const float* bk = (const float*)d_in[4];
    const float* Wv = (const float*)d_in[5];
    const float* bv = (const float*)d_in[6];
    const float* Wo = (const float*)d_in[7];
    const float* bo = (const float*)d_in[8];

    ushort* base = (ushort*)d_ws;
    ushort* xb  = base;                                  // 4M bf16
    ushort* wc  = xb  + (size_t)4 * 1024 * 1024;         // 3M  (Wq|Wk|Wv)
    ushort* wob = wc  + (size_t)3 * 1024 * 1024;         // 1M
    ushort* qws = wob + (size_t)1 * 1024 * 1024;         // 4M  Q^T [B,H,64,S] (pre-scaled)
    ushort* kws = qws + (size_t)4 * 1024 * 1024;         // 4M  K [B,H,S,64]
    ushort* vws = kws + (size_t)4 * 1024 * 1024;         // 4M  V^T [B,H,64,S]
    ushort* aws = vws + (size_t)4 * 1024 * 1024;         // 4M  attn out bf16

    hipLaunchKernelGGL(cvt_kernel, dim3(8192), dim3(256), 0, stream,
                       x, Wq, Wk, Wv, Wo, xb, wc, wob);

    hipLaunchKernelGGL((gemm_bf16<2, 0>), dim3(MTOT / 128, 3072 / 128), dim3(256), 0, stream,
                       xb, wc, bq, bk, bv, qws, kws, vws, (float*)nullptr);

    hipLaunchKernelGGL(attn_kernel, dim3(512), dim3(512), 0, stream,
                       qws, kws, vws, aws);

    hipLaunchKernelGGL((gemm_bf16<1, 1>), dim3(MTOT / 64, DMODEL / 128), dim3(256), 0, stream,
                       aws, wob, bo, (const float*)nullptr, (const float*)nullptr,
                       (ushort*)nullptr, (ushort*)nullptr, (ushort*)nullptr, (float*)d_out);
}